// Round 10
// baseline (112.132 us; speedup 1.0000x reference)
//
#include <hip/hip_runtime.h>
#include <hip/hip_fp16.h>

#define CCH 128
#define SV 24
#define NVOX 13824   // 24^3

typedef unsigned short u16;
typedef unsigned int   u32;

// unpack uint4 (8 packed fp16) -> 8 floats
__device__ __forceinline__ void cvt8h(uint4 r, float* f) {
    const __half2* h = (const __half2*)&r;
    const float2 a = __half22float2(h[0]);
    const float2 b = __half22float2(h[1]);
    const float2 c = __half22float2(h[2]);
    const float2 d = __half22float2(h[3]);
    f[0] = a.x; f[1] = a.y; f[2] = b.x; f[3] = b.y;
    f[4] = c.x; f[5] = c.y; f[6] = d.x; f[7] = d.y;
}
__device__ __forceinline__ u32 pack2h(float a, float b) {
    const __half2 h = __floats2half2_rn(a, b);
    return *(const u32*)&h;
}

// ---------------------------------------------------------------------------
// Projection GEMM (R8-proven, swizzle reverted): C[vox][o] = X*W^T + b.
// One m in {q,k,v} per blockIdx.y. Block = 64 vox x 128 o, K-tile 32.
// q -> d_out fp32; k/v -> ws packed fp16 + pad row (= bias) at NVOX.
// Grid (216, 3).
// ---------------------------------------------------------------------------
__global__ __launch_bounds__(256) void proj_kernel(
    const float* __restrict__ x,
    const float* __restrict__ wq, const float* __restrict__ bq,
    const float* __restrict__ wk, const float* __restrict__ bk,
    const float* __restrict__ wv, const float* __restrict__ bv,
    const float* __restrict__ relh, const float* __restrict__ relw,
    const float* __restrict__ reld,
    float* __restrict__ qout, u16* __restrict__ kws, u16* __restrict__ vws,
    float* __restrict__ biasW)
{
    const int m = blockIdx.y;                  // 0=q 1=k 2=v
    const float* __restrict__ w = (m == 0) ? wq : (m == 1) ? wk : wv;
    const float* __restrict__ b = (m == 0) ? bq : (m == 1) ? bk : bv;

    __shared__ float Xs[32][64];
    __shared__ float Ws[32][128];

    const int tid  = threadIdx.x;
    const int vox0 = blockIdx.x * 64;
    const int v0   = (tid & 15) * 4;
    const int o0   = (tid >> 4) * 8;

    const int xc  = tid >> 3;
    const int xv  = (tid & 7) * 4;
    const int wo  = tid >> 1;
    const int wkh = (tid & 1) * 16;

    float acc[4][8] = {{0.f}};

    for (int k0 = 0; k0 < CCH; k0 += 32) {
        {
            const float* src = x + (size_t)(k0 + xc) * NVOX + vox0 + xv;
            const float4 a0 = *(const float4*)src;
            const float4 a1 = *(const float4*)(src + 32);
            *(float4*)&Xs[xc][xv]      = a0;
            *(float4*)&Xs[xc][xv + 32] = a1;
        }
        {
            const float* src = w + (size_t)wo * CCH + k0 + wkh;
            const float4 b0 = *(const float4*)src;
            const float4 b1 = *(const float4*)(src + 4);
            const float4 b2 = *(const float4*)(src + 8);
            const float4 b3 = *(const float4*)(src + 12);
            Ws[wkh + 0][wo] = b0.x;  Ws[wkh + 1][wo] = b0.y;
            Ws[wkh + 2][wo] = b0.z;  Ws[wkh + 3][wo] = b0.w;
            Ws[wkh + 4][wo] = b1.x;  Ws[wkh + 5][wo] = b1.y;
            Ws[wkh + 6][wo] = b1.z;  Ws[wkh + 7][wo] = b1.w;
            Ws[wkh + 8][wo] = b2.x;  Ws[wkh + 9][wo] = b2.y;
            Ws[wkh + 10][wo] = b2.z; Ws[wkh + 11][wo] = b2.w;
            Ws[wkh + 12][wo] = b3.x; Ws[wkh + 13][wo] = b3.y;
            Ws[wkh + 14][wo] = b3.z; Ws[wkh + 15][wo] = b3.w;
        }
        __syncthreads();

#pragma unroll
        for (int k = 0; k < 32; ++k) {
            const float4 xf = *(const float4*)&Xs[k][v0];
            const float4 w0 = *(const float4*)&Ws[k][o0];
            const float4 w1 = *(const float4*)&Ws[k][o0 + 4];
            const float xr[4] = {xf.x, xf.y, xf.z, xf.w};
            const float wr[8] = {w0.x, w0.y, w0.z, w0.w,
                                 w1.x, w1.y, w1.z, w1.w};
#pragma unroll
            for (int vv = 0; vv < 4; ++vv)
#pragma unroll
                for (int oo = 0; oo < 8; ++oo)
                    acc[vv][oo] = fmaf(xr[vv], wr[oo], acc[vv][oo]);
        }
        __syncthreads();
    }

    const float4 bf0 = *(const float4*)(b + o0);
    const float4 bf1 = *(const float4*)(b + o0 + 4);
    const float br[8] = {bf0.x, bf0.y, bf0.z, bf0.w,
                         bf1.x, bf1.y, bf1.z, bf1.w};

#pragma unroll
    for (int vv = 0; vv < 4; ++vv) {
        float r[8];
#pragma unroll
        for (int oo = 0; oo < 8; ++oo) r[oo] = acc[vv][oo] + br[oo];
        const size_t row = (size_t)(vox0 + v0 + vv) * CCH + o0;
        if (m == 0) {
            float4 s0 = {r[0], r[1], r[2], r[3]};
            float4 s1 = {r[4], r[5], r[6], r[7]};
            *(float4*)(qout + row) = s0;
            *(float4*)(qout + row + 4) = s1;
        } else {
            u16* out = (m == 1) ? kws : vws;
            uint4 st = {pack2h(r[0], r[1]), pack2h(r[2], r[3]),
                        pack2h(r[4], r[5]), pack2h(r[6], r[7])};
            *(uint4*)(out + row) = st;
        }
    }

    if (blockIdx.x == 0) {
        if (m == 1 && tid < CCH) {
            const __half hb = __float2half_rn(bk[tid]);
            kws[(size_t)NVOX * CCH + tid] = *(const u16*)&hb;
        }
        if (m == 2 && tid < CCH) {
            const __half hb = __float2half_rn(bv[tid]);
            vws[(size_t)NVOX * CCH + tid] = *(const u16*)&hb;
        }
        if (m == 1 && tid < 27) {
            const int i = tid / 9, j = (tid / 3) % 3, l = tid % 3;
            float s = 0.f;
            for (int c = 0; c < 64; ++c)
                s += relh[c * 3 + i] + relw[c * 3 + j] + reld[c * 3 + l];
            biasW[tid] = s;
        }
    }
}

// ---------------------------------------------------------------------------
// Attention, LDS-halo version. Block = 4x4x2 voxel tile (32 vox), halo
// 6x6x4 = 144 k/v rows staged in LDS (fp16, row stride 136 u16 for 16B
// alignment + reduced bank conflicts). Two-phase: K-halo -> QK -> softmax,
// then V-halo overwrites the same buffer -> PV. Q tile fp32 in LDS
// (stride 132). No cross-lane shuffles anywhere. Grid 432, block 256.
// LDS total 59.5 KB -> 2 blocks/CU.
// ---------------------------------------------------------------------------
#define KSTR 136
#define QSTR 132

__global__ __launch_bounds__(256) void attn_kernel(
    float* __restrict__ qo, const u16* __restrict__ kws,
    const u16* __restrict__ vws, const float* __restrict__ biasW)
{
    __shared__ u16   KV[144 * KSTR];     // 39168 B  (K phase, then V phase)
    __shared__ float Qs[32 * QSTR];      // 16896 B
    __shared__ float probs[32 * 27];     //  3456 B

    const int tid = threadIdx.x;
    const int bx  = blockIdx.x;
    const int th = bx / 72, rb = bx % 72, tw = rb / 12, td = rb % 12;
    const int h0 = th * 4, w0 = tw * 4, d0 = td * 2;

    // ---- stage K halo: 144 rows x 16 uint4 = 2304 loads ----
#pragma unroll
    for (int it = 0; it < 9; ++it) {
        const int e   = it * 256 + tid;
        const int row = e >> 4, seg = e & 15;
        const int lh = row / 24, rr = row % 24, lw = rr >> 2, ld = rr & 3;
        const int nh = h0 + lh - 1, nw = w0 + lw - 1, nd = d0 + ld - 1;
        const bool ok = ((unsigned)nh < 24u) && ((unsigned)nw < 24u) &&
                        ((unsigned)nd < 24u);
        const int gv = ok ? ((nh * 24 + nw) * 24 + nd) : NVOX;
        const uint4 kv = *(const uint4*)(kws + (size_t)gv * CCH + seg * 8);
        *(uint4*)&KV[row * KSTR + seg * 8] = kv;
    }
    // ---- stage Q tile: 32 rows x 32 float4 = 1024 loads ----
#pragma unroll
    for (int it = 0; it < 4; ++it) {
        const int e = it * 256 + tid;
        const int v = e >> 5, seg = e & 31;
        const int gh = h0 + (v >> 3), gw = w0 + ((v >> 1) & 3),
                  gd = d0 + (v & 1);
        const int gv = (gh * 24 + gw) * 24 + gd;
        const float4 qv = *(const float4*)(qo + (size_t)gv * CCH + seg * 4);
        *(float4*)&Qs[v * QSTR + seg * 4] = qv;
    }
    __syncthreads();

    // ---- QK: thread = (vox, slot-group); slots {s0, s0+8, s0+16, s0+24} ----
    {
        const int v  = tid & 31;
        const int s0 = tid >> 5;         // 0..7
        const int vh = v >> 3, vw = (v >> 1) & 3, vd = v & 1;
        int r[4];
#pragma unroll
        for (int jj = 0; jj < 4; ++jj) {
            int s = s0 + jj * 8; if (s > 26) s = 26;   // clamped dup, unwritten
            const int i = s / 9, j = (s / 3) % 3, l = s % 3;
            r[jj] = (vh + i) * 24 + (vw + j) * 4 + (vd + l);
        }
        float acc[4] = {0.f, 0.f, 0.f, 0.f};
        for (int c = 0; c < 128; c += 8) {
            const float4 q0 = *(const float4*)&Qs[v * QSTR + c];
            const float4 q1 = *(const float4*)&Qs[v * QSTR + c + 4];
            const float qr[8] = {q0.x, q0.y, q0.z, q0.w,
                                 q1.x, q1.y, q1.z, q1.w};
#pragma unroll
            for (int jj = 0; jj < 4; ++jj) {
                const uint4 kr = *(const uint4*)&KV[r[jj] * KSTR + c];
                float f[8];
                cvt8h(kr, f);
                float p = acc[jj];
                p = fmaf(qr[0], f[0], p); p = fmaf(qr[1], f[1], p);
                p = fmaf(qr[2], f[2], p); p = fmaf(qr[3], f[3], p);
                p = fmaf(qr[4], f[4], p); p = fmaf(qr[5], f[5], p);
                p = fmaf(qr[6], f[6], p); p = fmaf(qr[7], f[7], p);
                acc[jj] = p;
            }
        }
#pragma unroll
        for (int jj = 0; jj < 4; ++jj) {
            const int s = s0 + jj * 8;
            if (s < 27) probs[v * 27 + s] = acc[jj];
        }
    }
    __syncthreads();

    // ---- softmax (32 threads) + stage V halo (all threads) ----
    if (tid < 32) {
        const int v = tid;
        float qsum = 0.f;
        for (int c = 0; c < 128; c += 4) {
            const float4 q = *(const float4*)&Qs[v * QSTR + c];
            qsum += q.x + q.y + q.z + q.w;
        }
        float L[27];
        float mx = -1e30f;
#pragma unroll
        for (int s = 0; s < 27; ++s) {
            L[s] = fmaf(qsum, biasW[s], probs[v * 27 + s]);
            mx = fmaxf(mx, L[s]);
        }
        float sum = 0.f;
#pragma unroll
        for (int s = 0; s < 27; ++s) { L[s] = __expf(L[s] - mx); sum += L[s]; }
        const float inv = 1.f / sum;
#pragma unroll
        for (int s = 0; s < 27; ++s) probs[v * 27 + s] = L[s] * inv;
    }
#pragma unroll
    for (int it = 0; it < 9; ++it) {
        const int e   = it * 256 + tid;
        const int row = e >> 4, seg = e & 15;
        const int lh = row / 24, rr = row % 24, lw = rr >> 2, ld = rr & 3;
        const int nh = h0 + lh - 1, nw = w0 + lw - 1, nd = d0 + ld - 1;
        const bool ok = ((unsigned)nh < 24u) && ((unsigned)nw < 24u) &&
                        ((unsigned)nd < 24u);
        const int gv = ok ? ((nh * 24 + nw) * 24 + nd) : NVOX;
        const uint4 vv = *(const uint4*)(vws + (size_t)gv * CCH + seg * 8);
        *(uint4*)&KV[row * KSTR + seg * 8] = vv;
    }
    __syncthreads();

    // ---- PV: thread = (vox, 16-ch group) ----
    {
        const int v  = tid & 31;
        const int cg = tid >> 5;         // 0..7
        const int c0 = cg * 16;
        const int vh = v >> 3, vw = (v >> 1) & 3, vd = v & 1;
        float acc[16];
#pragma unroll
        for (int e = 0; e < 16; ++e) acc[e] = 0.f;

#pragma unroll
        for (int s = 0; s < 27; ++s) {
            const int i = s / 9, j = (s / 3) % 3, l = s % 3;
            const int r = (vh + i) * 24 + (vw + j) * 4 + (vd + l);
            const float a = probs[v * 27 + s];
            const uint4 w0 = *(const uint4*)&KV[r * KSTR + c0];
            const uint4 w1 = *(const uint4*)&KV[r * KSTR + c0 + 8];
            float f[8];
            cvt8h(w0, f);
#pragma unroll
            for (int e = 0; e < 8; ++e) acc[e] = fmaf(a, f[e], acc[e]);
            cvt8h(w1, f);
#pragma unroll
            for (int e = 0; e < 8; ++e) acc[8 + e] = fmaf(a, f[e], acc[8 + e]);
        }

        const int gh = h0 + vh, gw = w0 + vw, gd = d0 + vd;
        float* dst = qo + (size_t)((gh * 24 + gw) * 24 + gd) * CCH + c0;
#pragma unroll
        for (int e = 0; e < 4; ++e) {
            float4 st = {acc[4 * e], acc[4 * e + 1],
                         acc[4 * e + 2], acc[4 * e + 3]};
            *(float4*)(dst + 4 * e) = st;
        }
    }
}

// ---------------------------------------------------------------------------
extern "C" void kernel_launch(void* const* d_in, const int* in_sizes, int n_in,
                              void* d_out, int out_size, void* d_ws,
                              size_t ws_size, hipStream_t stream)
{
    const float* x    = (const float*)d_in[0];
    const float* wq   = (const float*)d_in[1];
    const float* bq   = (const float*)d_in[2];
    const float* wk   = (const float*)d_in[3];
    const float* bk   = (const float*)d_in[4];
    const float* wv   = (const float*)d_in[5];
    const float* bv   = (const float*)d_in[6];
    const float* relh = (const float*)d_in[7];
    const float* relw = (const float*)d_in[8];
    const float* reld = (const float*)d_in[9];

    u16*   kws   = (u16*)d_ws;                         // (NVOX+1)*128 fp16
    u16*   vws   = kws + (size_t)(NVOX + 1) * CCH;     // (NVOX+1)*128 fp16
    float* biasW = (float*)(vws + (size_t)(NVOX + 1) * CCH);  // 27 fp32

    dim3 pgrid(NVOX / 64, 3);
    proj_kernel<<<pgrid, 256, 0, stream>>>(x, wq, bq, wk, bk, wv, bv,
                                           relh, relw, reld,
                                           (float*)d_out, kws, vws, biasW);
    attn_kernel<<<432, 256, 0, stream>>>((float*)d_out, kws, vws, biasW);
}